// Round 11
// baseline (12823.262 us; speedup 1.0000x reference)
//
#include <hip/hip_runtime.h>
#include <math.h>

// ---------------------------------------------------------------------------
// SequencePredictorGRU — fused persistent kernel, fp16 MFMA, fp32 accum.
// R11: 32-ROW BLOCKS (256 thr, 4 waves) to finally get real concurrency.
// R10 post-mortem: 64-row blocks need dbuf-LDS (146KB, 1 blk/CU) OR hnh regs
// (>128 VGPR, spills) — contradiction. At 32 rows: G1 acc[2][3]=24 regs,
// hnh[8][2]=32 held, peak ~110 <= 120; LDS ~35.6KB -> 4 blocks/CU = 16
// waves/CU = 4 waves/SIMD, and the 4 blocks are INDEPENDENT (no shared
// barriers) so barrier stalls in one block are covered by the others.
//  - h [32][512] f16 frag-order single buffer (32KB); h_new in hnh regs
//    (statically indexed, q fully unrolled — rule #20).
//  - init: two 16-row halves; t1-half [16][1024] (32KB) aliases h region.
//  - G2 epilogue constants staged f16 in LDS (2KB); c7 gate coefs read from
//    global each pass (L2-hot, transient regs).
// Frag-order h (32 rows): fah(m,k) = ((k>>5)*2+(m>>4))*1024
//   + ((m&15)+((k>>3)&3)*16)*16 + (k&7)*2 ; B-frag read = base+chunk*1024+lane*16.
// t1 (16 rows): fa16(m,k) = (k>>5)*1024 + ((m&15)+((k>>3)&3)*16)*16 + (k&7)*2.
// MFMA 16x16x32 layouts (verified R1-R10):
//   A: row=l&15, k=(l>>4)*8+i     B: col=l&15, k=(l>>4)*8+i
//   D: col=l&15 (-> m row), row=(l>>4)*4+r (-> j, contiguous quad)
// ---------------------------------------------------------------------------

typedef _Float16 f16;
typedef _Float16 f16x4 __attribute__((ext_vector_type(4)));
typedef _Float16 f16x8 __attribute__((ext_vector_type(8)));
typedef float f32x4 __attribute__((ext_vector_type(4)));

#define TSTEPS 20

__device__ __forceinline__ float sigm(float v) { return 1.0f / (1.0f + __expf(-v)); }
__device__ __forceinline__ float tanh_s(float v) {
  float e = __expf(-2.0f * fabsf(v));
  float r = (1.0f - e) / (1.0f + e);
  return copysignf(r, v);
}
__device__ __forceinline__ float gelu_e(float v) {
  return 0.5f * v * (1.0f + erff(v * 0.70710678118654752f));
}

// frag-order byte address, 32-row h buffer (chunks (k>>5)*2 + (m>>4), 32KB)
__device__ __forceinline__ int fah(int m, int k) {
  return (((k >> 5) * 2 + (m >> 4)) << 10) + (((m & 15) + ((k >> 3) & 3) * 16) << 4) + ((k & 7) * 2);
}
// frag-order byte address, 16-row t1 half (chunk k>>5, 32KB, k<1024)
__device__ __forceinline__ int fa16(int m, int k) {
  return ((k >> 5) << 10) + (((m & 15) + ((k >> 3) & 3) * 16) << 4) + ((k & 7) * 2);
}

// ---------------------------------------------------------------------------
// Prologue: fp16 weights (K-contiguous) + packed f16 gate coefficients.
// c7 layout [7][512]: 0 Wih_r, 1 Wih_z, 2 Wih_n, 3 bih_r+bhh_r, 4 bih_z+bhh_z,
//                     5 bih_n, 6 bhh_n
// ---------------------------------------------------------------------------
__global__ void cvt_weights(const float* __restrict__ W1, const float* __restrict__ W2,
                            const float* __restrict__ Whh, const float* __restrict__ Wo1,
                            const float* __restrict__ Wih, const float* __restrict__ bih,
                            const float* __restrict__ bhh,
                            f16* __restrict__ w1t, f16* __restrict__ w2t,
                            f16* __restrict__ whh, f16* __restrict__ wo1t,
                            f16* __restrict__ c7) {
  int i = blockIdx.x * 256 + threadIdx.x;
  if (i < 163840) { int n = i / 160; int k = i - n * 160; w1t[i] = (f16)W1[k * 1024 + n]; return; }
  i -= 163840;
  if (i < 524288) { int n = i >> 10; int k = i & 1023; w2t[i] = (f16)W2[k * 512 + n]; return; }
  i -= 524288;
  if (i < 786432) { whh[i] = (f16)Whh[i]; return; }
  i -= 786432;
  if (i < 131072) { int o = i >> 9; int k = i & 511; wo1t[i] = (f16)Wo1[k * 256 + o]; return; }
  i -= 131072;
  if (i < 3584) {
    const int which = i >> 9, j = i & 511;
    float v;
    if (which == 0) v = Wih[j];
    else if (which == 1) v = Wih[512 + j];
    else if (which == 2) v = Wih[1024 + j];
    else if (which == 3) v = bih[j] + bhh[j];
    else if (which == 4) v = bih[512 + j] + bhh[512 + j];
    else if (which == 5) v = bih[1024 + j];
    else v = bhh[1024 + j];
    c7[i] = (f16)v;
  }
}

// ---------------------------------------------------------------------------
// Main fused kernel: 256 threads = 4 waves, 32 rows/block, target 4 blocks/CU.
// ---------------------------------------------------------------------------
__global__ __launch_bounds__(256, 4)
void gru_main(
    const float* __restrict__ zq, const float* __restrict__ fpr,
    const float* __restrict__ b1, const float* __restrict__ g1, const float* __restrict__ be1,
    const float* __restrict__ b2, const float* __restrict__ stok,
    const float* __restrict__ bo1, const float* __restrict__ go, const float* __restrict__ beo,
    const float* __restrict__ Wo2, const float* __restrict__ bo2,
    const f16* __restrict__ w1t, const f16* __restrict__ w2t,
    const f16* __restrict__ whh, const f16* __restrict__ wo1t,
    const f16* __restrict__ c7,
    float* __restrict__ out) {
  __shared__ __align__(16) unsigned char sm[32768];  // h [32][512] / t1-half [16][1024]
  __shared__ float sm_s[128], sm_ss[128], sm_yp[128];
  __shared__ float sm_x[32];
  __shared__ __align__(8) f16 sm_aux[1024];  // bo1|go|beo|Wo2 (f16), 256 each

  const int tid = threadIdx.x;
  const int w = tid >> 6;        // 0..3
  const int lane = tid & 63;
  const int l16 = lane & 15;
  const int l4 = lane >> 4;
  const int R0 = blockIdx.x * 32;

  const float bo2v = bo2[0];
  if (tid < 32) sm_x[tid] = stok[0];
  for (int i = tid; i < 1024; i += 256) {
    const float v = (i < 256) ? bo1[i] : (i < 512) ? go[i - 256] : (i < 768) ? beo[i - 512] : Wo2[i - 768];
    sm_aux[i] = (f16)v;
  }

  // ======================= init_mlp (two 16-row halves) ====================
  f16x4 h0h[2][8];  // [hh][pp] — statically indexed (fully unrolled)

  #pragma unroll
  for (int hh = 0; hh < 2; ++hh) {
    const int RH = R0 + hh * 16;
    // ---- G0a: t1 = cat(zq,fpr) @ W1 + b1 -> t1 half (frag order) ----------
    #pragma unroll 1
    for (int q = 0; q < 8; ++q) {
      const int jq0 = w * 256 + q * 32;
      f32x4 acc[2];
      #pragma unroll
      for (int jh = 0; jh < 2; ++jh) acc[jh] = (f32x4){0.f, 0.f, 0.f, 0.f};
      #pragma unroll
      for (int kf = 0; kf < 5; ++kf) {
        const int k0 = kf * 32 + l4 * 8;
        const int gm = RH + l16;
        const float* src = (kf < 4) ? (zq + gm * 128 + k0) : (fpr + gm * 32 + (k0 - 128));
        float4 v0 = *(const float4*)src;
        float4 v1 = *(const float4*)(src + 4);
        f16x8 B;
        B[0] = (f16)v0.x; B[1] = (f16)v0.y; B[2] = (f16)v0.z; B[3] = (f16)v0.w;
        B[4] = (f16)v1.x; B[5] = (f16)v1.y; B[6] = (f16)v1.z; B[7] = (f16)v1.w;
        #pragma unroll
        for (int jh = 0; jh < 2; ++jh) {
          const f16x8 A = *(const f16x8*)(w1t + (jq0 + jh * 16 + l16) * 160 + k0);
          acc[jh] = __builtin_amdgcn_mfma_f32_16x16x32_f16(A, B, acc[jh], 0, 0, 0);
        }
      }
      #pragma unroll
      for (int jh = 0; jh < 2; ++jh) {
        const int jq = jq0 + jh * 16 + l4 * 4;
        const float4 bb = *(const float4*)(b1 + jq);
        f16x4 v;
        v[0] = (f16)(acc[jh][0] + bb.x); v[1] = (f16)(acc[jh][1] + bb.y);
        v[2] = (f16)(acc[jh][2] + bb.z); v[3] = (f16)(acc[jh][3] + bb.w);
        *(f16x4*)(sm + fa16(l16, jq)) = v;
      }
    }
    __syncthreads();
    // ---- LN(1024) + GELU in place: row = tid>>4, 64-col strip per thread --
    {
      const int m = tid >> 4;          // 0..15
      const int c0 = (tid & 15) * 64;
      float s = 0.f, ss = 0.f;
      #pragma unroll
      for (int i = 0; i < 8; ++i) {
        f16x8 v = *(const f16x8*)(sm + fa16(m, c0 + i * 8));
        #pragma unroll
        for (int j = 0; j < 8; ++j) { float f = (float)v[j]; s += f; ss += f * f; }
      }
      s += __shfl_xor(s, 1); ss += __shfl_xor(ss, 1);
      s += __shfl_xor(s, 2); ss += __shfl_xor(ss, 2);
      s += __shfl_xor(s, 4); ss += __shfl_xor(ss, 4);
      s += __shfl_xor(s, 8); ss += __shfl_xor(ss, 8);
      const float mean = s * (1.f / 1024.f);
      const float rstd = rsqrtf(ss * (1.f / 1024.f) - mean * mean + 1e-5f);
      #pragma unroll 2
      for (int i = 0; i < 8; ++i) {
        const int c = c0 + i * 8;
        f16x8 v = *(const f16x8*)(sm + fa16(m, c));
        float4 ga = *(const float4*)(g1 + c);
        float4 gb = *(const float4*)(g1 + c + 4);
        float4 ba = *(const float4*)(be1 + c);
        float4 bb = *(const float4*)(be1 + c + 4);
        float gs[8] = {ga.x, ga.y, ga.z, ga.w, gb.x, gb.y, gb.z, gb.w};
        float bs[8] = {ba.x, ba.y, ba.z, ba.w, bb.x, bb.y, bb.z, bb.w};
        f16x8 o;
        #pragma unroll
        for (int j = 0; j < 8; ++j)
          o[j] = (f16)gelu_e(((float)v[j] - mean) * rstd * gs[j] + bs[j]);
        *(f16x8*)(sm + fa16(m, c)) = o;
      }
    }
    __syncthreads();
    // ---- G0b: h0_half = tanh(t1g @ W2 + b2) -> regs -----------------------
    #pragma unroll
    for (int pp = 0; pp < 8; ++pp) {
      const int jq0 = w * 128 + pp * 16;
      f32x4 acc = (f32x4){0.f, 0.f, 0.f, 0.f};
      #pragma unroll 4
      for (int kf = 0; kf < 32; ++kf) {
        const f16x8 B = *(const f16x8*)(sm + (kf << 10) + lane * 16);
        const f16x8 A = *(const f16x8*)(w2t + (jq0 + l16) * 1024 + kf * 32 + l4 * 8);
        acc = __builtin_amdgcn_mfma_f32_16x16x32_f16(A, B, acc, 0, 0, 0);
      }
      const int jq = jq0 + l4 * 4;
      const float4 bb = *(const float4*)(b2 + jq);
      f16x4 v;
      v[0] = (f16)tanh_s(acc[0] + bb.x); v[1] = (f16)tanh_s(acc[1] + bb.y);
      v[2] = (f16)tanh_s(acc[2] + bb.z); v[3] = (f16)tanh_s(acc[3] + bb.w);
      h0h[hh][pp] = v;
    }
    __syncthreads();  // all t1 reads done; region reusable
  }
  // ---- commit h0 (frag order, 32 rows) ------------------------------------
  #pragma unroll
  for (int hh = 0; hh < 2; ++hh)
    #pragma unroll
    for (int pp = 0; pp < 8; ++pp) {
      const int jq = w * 128 + pp * 16 + l4 * 4;
      *(f16x4*)(sm + fah(hh * 16 + l16, jq)) = h0h[hh][pp];
    }
  __syncthreads();

  // ============================ GRU loop ===================================
  #pragma unroll 1
  for (int t = 0; t < TSTEPS; ++t) {
    // ---- G1: gates = Whh · h^T (8 q-passes of 16 j), blend -> hnh regs ----
    f16x4 hnh[8][2];  // [q][mt] — statically indexed (q fully unrolled)
    #pragma unroll
    for (int q = 0; q < 8; ++q) {
      const int jt = w * 128 + q * 16;
      f32x4 acc[2][3];
      #pragma unroll
      for (int mt = 0; mt < 2; ++mt)
        #pragma unroll
        for (int g = 0; g < 3; ++g) acc[mt][g] = (f32x4){0.f, 0.f, 0.f, 0.f};
      #pragma unroll 2
      for (int kf = 0; kf < 16; ++kf) {
        f16x8 B[2];
        B[0] = *(const f16x8*)(sm + ((kf * 2 + 0) << 10) + lane * 16);
        B[1] = *(const f16x8*)(sm + ((kf * 2 + 1) << 10) + lane * 16);
        #pragma unroll
        for (int g = 0; g < 3; ++g) {
          const f16x8 A = *(const f16x8*)(whh + (g * 512 + jt + l16) * 512 + kf * 32 + l4 * 8);
          acc[0][g] = __builtin_amdgcn_mfma_f32_16x16x32_f16(A, B[0], acc[0][g], 0, 0, 0);
          acc[1][g] = __builtin_amdgcn_mfma_f32_16x16x32_f16(A, B[1], acc[1][g], 0, 0, 0);
        }
      }
      if (q == 0) __syncthreads();  // B5: sm_x(t) visible (hidden behind q0 MFMA)
      const int jq = jt + l4 * 4;
      const f16x4 wrh = *(const f16x4*)(c7 + jq);
      const f16x4 wzh = *(const f16x4*)(c7 + 512 + jq);
      const f16x4 wnh = *(const f16x4*)(c7 + 1024 + jq);
      const f16x4 crh = *(const f16x4*)(c7 + 1536 + jq);
      const f16x4 czh = *(const f16x4*)(c7 + 2048 + jq);
      const f16x4 bnh = *(const f16x4*)(c7 + 2560 + jq);
      const f16x4 cnh = *(const f16x4*)(c7 + 3072 + jq);
      #pragma unroll
      for (int mt = 0; mt < 2; ++mt) {
        const int m = mt * 16 + l16;
        const float x = sm_x[m];
        const f16x4 ho = *(const f16x4*)(sm + fah(m, jq));
        f16x4 hn;
        #pragma unroll
        for (int r = 0; r < 4; ++r) {
          const float gr = sigm(x * (float)wrh[r] + (float)crh[r] + acc[mt][0][r]);
          const float gz = sigm(x * (float)wzh[r] + (float)czh[r] + acc[mt][1][r]);
          const float gn = tanh_s(x * (float)wnh[r] + (float)bnh[r] + gr * (acc[mt][2][r] + (float)cnh[r]));
          hn[r] = (f16)((1.f - gz) * gn + gz * (float)ho[r]);
        }
        hnh[q][mt] = hn;
      }
    }
    __syncthreads();  // B1: all reads of h(t) done
    #pragma unroll
    for (int q = 0; q < 8; ++q) {
      const int jq = w * 128 + q * 16 + l4 * 4;
      #pragma unroll
      for (int mt = 0; mt < 2; ++mt)
        *(f16x4*)(sm + fah(mt * 16 + l16, jq)) = hnh[q][mt];
    }
    __syncthreads();  // B2: h(t+1) committed
    // ---- G2: y = gelu(LN(h_new @ Wo1 + bo1)) @ Wo2 + bo2 ------------------
    {
      f32x4 a2[2][4];  // [mt][jt2] — wave j-slice = 64
      #pragma unroll
      for (int mt = 0; mt < 2; ++mt)
        #pragma unroll
        for (int jt2 = 0; jt2 < 4; ++jt2) a2[mt][jt2] = (f32x4){0.f, 0.f, 0.f, 0.f};
      #pragma unroll 2
      for (int kf = 0; kf < 16; ++kf) {
        f16x8 B[2];
        B[0] = *(const f16x8*)(sm + ((kf * 2 + 0) << 10) + lane * 16);
        B[1] = *(const f16x8*)(sm + ((kf * 2 + 1) << 10) + lane * 16);
        #pragma unroll
        for (int jt2 = 0; jt2 < 4; ++jt2) {
          const f16x8 A = *(const f16x8*)(wo1t + (w * 64 + jt2 * 16 + l16) * 512 + kf * 32 + l4 * 8);
          a2[0][jt2] = __builtin_amdgcn_mfma_f32_16x16x32_f16(A, B[0], a2[0][jt2], 0, 0, 0);
          a2[1][jt2] = __builtin_amdgcn_mfma_f32_16x16x32_f16(A, B[1], a2[1][jt2], 0, 0, 0);
        }
      }
      float vv[2][4][4];
      #pragma unroll
      for (int mt = 0; mt < 2; ++mt) {
        float s = 0.f, ss = 0.f;
        #pragma unroll
        for (int jt2 = 0; jt2 < 4; ++jt2) {
          const f16x4 bo1v = *(const f16x4*)(sm_aux + w * 64 + jt2 * 16 + l4 * 4);
          #pragma unroll
          for (int r = 0; r < 4; ++r) {
            const float v = a2[mt][jt2][r] + (float)bo1v[r];
            vv[mt][jt2][r] = v; s += v; ss += v * v;
          }
        }
        s += __shfl_xor(s, 16); ss += __shfl_xor(ss, 16);
        s += __shfl_xor(s, 32); ss += __shfl_xor(ss, 32);
        if (l4 == 0) {
          const int m = mt * 16 + l16;
          sm_s[m * 4 + w] = s;
          sm_ss[m * 4 + w] = ss;
        }
      }
      __syncthreads();  // B3: stats partials visible
      #pragma unroll
      for (int mt = 0; mt < 2; ++mt) {
        const int m = mt * 16 + l16;
        float4 ps = *(const float4*)(sm_s + m * 4);
        float4 pq = *(const float4*)(sm_ss + m * 4);
        const float mean = (ps.x + ps.y + ps.z + ps.w) * (1.f / 256.f);
        const float q2 = (pq.x + pq.y + pq.z + pq.w) * (1.f / 256.f);
        const float rstd = rsqrtf(q2 - mean * mean + 1e-5f);
        float y = 0.f;
        #pragma unroll
        for (int jt2 = 0; jt2 < 4; ++jt2) {
          const int jb = w * 64 + jt2 * 16 + l4 * 4;
          const f16x4 gov = *(const f16x4*)(sm_aux + 256 + jb);
          const f16x4 bev = *(const f16x4*)(sm_aux + 512 + jb);
          const f16x4 wv  = *(const f16x4*)(sm_aux + 768 + jb);
          #pragma unroll
          for (int r = 0; r < 4; ++r)
            y += gelu_e((vv[mt][jt2][r] - mean) * rstd * (float)gov[r] + (float)bev[r]) * (float)wv[r];
        }
        y += __shfl_xor(y, 16);
        y += __shfl_xor(y, 32);
        if (l4 == 0) sm_yp[m * 4 + w] = y;
      }
      __syncthreads();  // B4: y partials visible
      if (tid < 32) {
        float4 ps = *(const float4*)(sm_yp + tid * 4);
        const float y = bo2v + ps.x + ps.y + ps.z + ps.w;
        sm_x[tid] = y;
        out[(R0 + tid) * 20 + t] = y;
      }
      // next step's B5 (inside q0) covers sm_x visibility
    }
  }
}

// ---------------------------------------------------------------------------
extern "C" void kernel_launch(void* const* d_in, const int* in_sizes, int n_in,
                              void* d_out, int out_size, void* d_ws, size_t ws_size,
                              hipStream_t stream) {
  const float* zq   = (const float*)d_in[0];
  const float* fpr  = (const float*)d_in[1];
  const float* W1   = (const float*)d_in[2];
  const float* b1   = (const float*)d_in[3];
  const float* g1   = (const float*)d_in[4];
  const float* be1  = (const float*)d_in[5];
  const float* W2   = (const float*)d_in[6];
  const float* b2   = (const float*)d_in[7];
  const float* stok = (const float*)d_in[8];
  const float* Wih  = (const float*)d_in[9];
  const float* Whh  = (const float*)d_in[10];
  const float* bih  = (const float*)d_in[11];
  const float* bhh  = (const float*)d_in[12];
  const float* Wo1  = (const float*)d_in[13];
  const float* bo1  = (const float*)d_in[14];
  const float* go   = (const float*)d_in[15];
  const float* beo  = (const float*)d_in[16];
  const float* Wo2  = (const float*)d_in[17];
  const float* bo2  = (const float*)d_in[18];

  char* ws = (char*)d_ws;
  f16* w1t  = (f16*)(ws + 0);        // 1024*160*2  = 327680
  f16* w2t  = (f16*)(ws + 327680);   // 512*1024*2  = 1048576
  f16* whh  = (f16*)(ws + 1376256);  // 1536*512*2  = 1572864
  f16* wo1t = (f16*)(ws + 2949120);  // 256*512*2   = 262144
  f16* c7   = (f16*)(ws + 3211264);  // 7*512*2     = 7168   (total ~3.2MB)

  cvt_weights<<<6287, 256, 0, stream>>>(W1, W2, Whh, Wo1, Wih, bih, bhh,
                                        w1t, w2t, whh, wo1t, c7);

  const int N = in_sizes[0] / 128;  // 65536 rows
  gru_main<<<N / 32, 256, 0, stream>>>(zq, fpr, b1, g1, be1, b2, stok,
                                       bo1, go, beo, Wo2, bo2,
                                       w1t, w2t, whh, wo1t, c7, (float*)d_out);
}

// Round 12
// 9268.472 us; speedup vs baseline: 1.3835x; 1.3835x over previous
//
#include <hip/hip_runtime.h>
#include <math.h>

// ---------------------------------------------------------------------------
// SequencePredictorGRU — fused persistent kernel, fp16 MFMA, fp32 accum.
// R12: 512-thr LB(512,2) block (the ONLY config with a verified 128-reg
// budget, R1/R7/R9) owning 32 ROWS with double-buffered h (2x32KB).
// Unified-file rule (R11 post-mortem): waves/SIMD gated by arch+AGPR total;
// acc[2][3]=24 AGPR + ~80 arch ~= 104 <= 128 -> 4 waves/SIMD; LDS ~74.6KB ->
// 2 independent blocks/CU (one block's barrier stalls covered by the other).
//  - h dbuf: buf=(t&1)<<15 within sm[64KB]; h_new written DIRECTLY to nxt
//    (no hold regs, no WAR barrier).
//  - init single-pass: t1[32][1024] frag-order = 64KB fills the region;
//    h0 held in 16 regs across the region-reuse barrier.
//  - c7 gate coefs (7KB) + G2 epilogue consts (2KB f16) staged in LDS.
// Frag-order (32 rows): fa32(m,k) = ((k>>5)*2+(m>>4))*1024
//   + ((m&15)+((k>>3)&3)*16)*16 + (k&7)*2   (t1: k<1024; h: k<512 + buf).
// B-frag read = base + chunk*1024 + lane*16 (linear, conflict-free).
// MFMA 16x16x32 layouts (verified R1-R11):
//   A: row=l&15, k=(l>>4)*8+i     B: col=l&15, k=(l>>4)*8+i
//   D: col=l&15 (-> m row), row=(l>>4)*4+r (-> j, contiguous quad)
// ---------------------------------------------------------------------------

typedef _Float16 f16;
typedef _Float16 f16x4 __attribute__((ext_vector_type(4)));
typedef _Float16 f16x8 __attribute__((ext_vector_type(8)));
typedef float f32x4 __attribute__((ext_vector_type(4)));

#define TSTEPS 20

__device__ __forceinline__ float sigm(float v) { return 1.0f / (1.0f + __expf(-v)); }
__device__ __forceinline__ float tanh_s(float v) {
  float e = __expf(-2.0f * fabsf(v));
  float r = (1.0f - e) / (1.0f + e);
  return copysignf(r, v);
}
__device__ __forceinline__ float gelu_e(float v) {
  return 0.5f * v * (1.0f + erff(v * 0.70710678118654752f));
}

// frag-order byte address, 32 rows (chunks (k>>5)*2 + (m>>4))
__device__ __forceinline__ int fa32(int m, int k) {
  return (((k >> 5) * 2 + (m >> 4)) << 10) + (((m & 15) + ((k >> 3) & 3) * 16) << 4) + ((k & 7) * 2);
}

// ---------------------------------------------------------------------------
// Prologue: fp16 weights (K-contiguous) + packed f16 gate coefficients.
// c7 layout [7][512]: 0 Wih_r, 1 Wih_z, 2 Wih_n, 3 bih_r+bhh_r, 4 bih_z+bhh_z,
//                     5 bih_n, 6 bhh_n
// ---------------------------------------------------------------------------
__global__ void cvt_weights(const float* __restrict__ W1, const float* __restrict__ W2,
                            const float* __restrict__ Whh, const float* __restrict__ Wo1,
                            const float* __restrict__ Wih, const float* __restrict__ bih,
                            const float* __restrict__ bhh,
                            f16* __restrict__ w1t, f16* __restrict__ w2t,
                            f16* __restrict__ whh, f16* __restrict__ wo1t,
                            f16* __restrict__ c7) {
  int i = blockIdx.x * 256 + threadIdx.x;
  if (i < 163840) { int n = i / 160; int k = i - n * 160; w1t[i] = (f16)W1[k * 1024 + n]; return; }
  i -= 163840;
  if (i < 524288) { int n = i >> 10; int k = i & 1023; w2t[i] = (f16)W2[k * 512 + n]; return; }
  i -= 524288;
  if (i < 786432) { whh[i] = (f16)Whh[i]; return; }
  i -= 786432;
  if (i < 131072) { int o = i >> 9; int k = i & 511; wo1t[i] = (f16)Wo1[k * 256 + o]; return; }
  i -= 131072;
  if (i < 3584) {
    const int which = i >> 9, j = i & 511;
    float v;
    if (which == 0) v = Wih[j];
    else if (which == 1) v = Wih[512 + j];
    else if (which == 2) v = Wih[1024 + j];
    else if (which == 3) v = bih[j] + bhh[j];
    else if (which == 4) v = bih[512 + j] + bhh[512 + j];
    else if (which == 5) v = bih[1024 + j];
    else v = bhh[1024 + j];
    c7[i] = (f16)v;
  }
}

// ---------------------------------------------------------------------------
// Main fused kernel: 512 threads = 8 waves, 32 rows/block, target 2 blocks/CU.
// ---------------------------------------------------------------------------
__global__ __launch_bounds__(512, 2)
void gru_main(
    const float* __restrict__ zq, const float* __restrict__ fpr,
    const float* __restrict__ b1, const float* __restrict__ g1, const float* __restrict__ be1,
    const float* __restrict__ b2, const float* __restrict__ stok,
    const float* __restrict__ bo1, const float* __restrict__ go, const float* __restrict__ beo,
    const float* __restrict__ Wo2, const float* __restrict__ bo2,
    const f16* __restrict__ w1t, const f16* __restrict__ w2t,
    const f16* __restrict__ whh, const f16* __restrict__ wo1t,
    const f16* __restrict__ c7,
    float* __restrict__ out) {
  __shared__ __align__(16) unsigned char sm[65536];  // h dbuf 2x32KB / t1[32][1024]
  __shared__ float sm_s[128], sm_ss[128], sm_yp[128];
  __shared__ float sm_x[32];
  __shared__ __align__(8) f16 sm_c7[3584];
  __shared__ __align__(8) f16 sm_aux[1024];  // bo1|go|beo|Wo2 (f16), 256 each

  const int tid = threadIdx.x;
  const int w = tid >> 6;        // 0..7
  const int lane = tid & 63;
  const int l16 = lane & 15;
  const int l4 = lane >> 4;
  const int R0 = blockIdx.x * 32;

  const float bo2v = bo2[0];
  if (tid < 32) sm_x[tid] = stok[0];
  for (int i = tid; i < 1792; i += 512)
    ((unsigned*)sm_c7)[i] = ((const unsigned*)c7)[i];
  for (int i = tid; i < 1024; i += 512) {
    const float v = (i < 256) ? bo1[i] : (i < 512) ? go[i - 256] : (i < 768) ? beo[i - 512] : Wo2[i - 768];
    sm_aux[i] = (f16)v;
  }

  // =============== G0a: t1 = cat(zq,fpr) @ W1 + b1 (single pass) ===========
  #pragma unroll 1
  for (int q = 0; q < 8; ++q) {
    const int jq0 = w * 128 + q * 16;
    f32x4 acc[2];
    #pragma unroll
    for (int mt = 0; mt < 2; ++mt) acc[mt] = (f32x4){0.f, 0.f, 0.f, 0.f};
    #pragma unroll
    for (int kf = 0; kf < 5; ++kf) {
      const int k0 = kf * 32 + l4 * 8;
      f16x8 B[2];
      #pragma unroll
      for (int mt = 0; mt < 2; ++mt) {
        const int gm = R0 + mt * 16 + l16;
        const float* src = (kf < 4) ? (zq + gm * 128 + k0) : (fpr + gm * 32 + (k0 - 128));
        float4 v0 = *(const float4*)src;
        float4 v1 = *(const float4*)(src + 4);
        f16x8 b;
        b[0] = (f16)v0.x; b[1] = (f16)v0.y; b[2] = (f16)v0.z; b[3] = (f16)v0.w;
        b[4] = (f16)v1.x; b[5] = (f16)v1.y; b[6] = (f16)v1.z; b[7] = (f16)v1.w;
        B[mt] = b;
      }
      const f16x8 A = *(const f16x8*)(w1t + (jq0 + l16) * 160 + k0);
      #pragma unroll
      for (int mt = 0; mt < 2; ++mt)
        acc[mt] = __builtin_amdgcn_mfma_f32_16x16x32_f16(A, B[mt], acc[mt], 0, 0, 0);
    }
    const int jq = jq0 + l4 * 4;
    const float4 bb = *(const float4*)(b1 + jq);
    #pragma unroll
    for (int mt = 0; mt < 2; ++mt) {
      f16x4 v;
      v[0] = (f16)(acc[mt][0] + bb.x); v[1] = (f16)(acc[mt][1] + bb.y);
      v[2] = (f16)(acc[mt][2] + bb.z); v[3] = (f16)(acc[mt][3] + bb.w);
      *(f16x4*)(sm + fa32(mt * 16 + l16, jq)) = v;
    }
  }
  __syncthreads();
  // =============== LN(1024) + GELU in place (16 thr/row) ===================
  {
    const int m = tid >> 4;          // 0..31
    const int c0 = (tid & 15) * 64;
    float s = 0.f, ss = 0.f;
    #pragma unroll
    for (int i = 0; i < 8; ++i) {
      f16x8 v = *(const f16x8*)(sm + fa32(m, c0 + i * 8));
      #pragma unroll
      for (int j = 0; j < 8; ++j) { float f = (float)v[j]; s += f; ss += f * f; }
    }
    s += __shfl_xor(s, 1); ss += __shfl_xor(ss, 1);
    s += __shfl_xor(s, 2); ss += __shfl_xor(ss, 2);
    s += __shfl_xor(s, 4); ss += __shfl_xor(ss, 4);
    s += __shfl_xor(s, 8); ss += __shfl_xor(ss, 8);
    const float mean = s * (1.f / 1024.f);
    const float rstd = rsqrtf(ss * (1.f / 1024.f) - mean * mean + 1e-5f);
    #pragma unroll 2
    for (int i = 0; i < 8; ++i) {
      const int c = c0 + i * 8;
      f16x8 v = *(const f16x8*)(sm + fa32(m, c));
      float4 ga = *(const float4*)(g1 + c);
      float4 gb = *(const float4*)(g1 + c + 4);
      float4 ba = *(const float4*)(be1 + c);
      float4 bb = *(const float4*)(be1 + c + 4);
      float gs[8] = {ga.x, ga.y, ga.z, ga.w, gb.x, gb.y, gb.z, gb.w};
      float bs[8] = {ba.x, ba.y, ba.z, ba.w, bb.x, bb.y, bb.z, bb.w};
      f16x8 o;
      #pragma unroll
      for (int j = 0; j < 8; ++j)
        o[j] = (f16)gelu_e(((float)v[j] - mean) * rstd * gs[j] + bs[j]);
      *(f16x8*)(sm + fa32(m, c)) = o;
    }
  }
  __syncthreads();
  // =============== G0b: h0 = tanh(t1g @ W2 + b2) -> regs ===================
  f16x4 h0h[4][2];  // [pp][mt] — statically indexed (fully unrolled)
  #pragma unroll
  for (int pp = 0; pp < 4; ++pp) {
    const int jq0 = w * 64 + pp * 16;
    f32x4 acc[2];
    #pragma unroll
    for (int mt = 0; mt < 2; ++mt) acc[mt] = (f32x4){0.f, 0.f, 0.f, 0.f};
    #pragma unroll 2
    for (int kf = 0; kf < 32; ++kf) {
      f16x8 B[2];
      #pragma unroll
      for (int mt = 0; mt < 2; ++mt)
        B[mt] = *(const f16x8*)(sm + ((kf * 2 + mt) << 10) + lane * 16);
      const f16x8 A = *(const f16x8*)(w2t + (jq0 + l16) * 1024 + kf * 32 + l4 * 8);
      #pragma unroll
      for (int mt = 0; mt < 2; ++mt)
        acc[mt] = __builtin_amdgcn_mfma_f32_16x16x32_f16(A, B[mt], acc[mt], 0, 0, 0);
    }
    const int jq = jq0 + l4 * 4;
    const float4 bb = *(const float4*)(b2 + jq);
    #pragma unroll
    for (int mt = 0; mt < 2; ++mt) {
      f16x4 v;
      v[0] = (f16)tanh_s(acc[mt][0] + bb.x); v[1] = (f16)tanh_s(acc[mt][1] + bb.y);
      v[2] = (f16)tanh_s(acc[mt][2] + bb.z); v[3] = (f16)tanh_s(acc[mt][3] + bb.w);
      h0h[pp][mt] = v;
    }
  }
  __syncthreads();  // all t1 reads done; region reusable as h dbuf
  #pragma unroll
  for (int pp = 0; pp < 4; ++pp) {
    const int jq = w * 64 + pp * 16 + l4 * 4;
    #pragma unroll
    for (int mt = 0; mt < 2; ++mt)
      *(f16x4*)(sm + fa32(mt * 16 + l16, jq)) = h0h[pp][mt];  // buffer 0
  }
  __syncthreads();

  // ============================ GRU loop ===================================
  #pragma unroll 1
  for (int t = 0; t < TSTEPS; ++t) {
    const int cur = (t & 1) << 15;
    const int nxt = cur ^ 32768;
    // ---- G1: gates = Whh · h^T (4 q-passes of 16 j), blend -> h[nxt] ------
    #pragma unroll 1
    for (int q = 0; q < 4; ++q) {
      const int jt = w * 64 + q * 16;
      f32x4 acc[2][3];
      #pragma unroll
      for (int mt = 0; mt < 2; ++mt)
        #pragma unroll
        for (int g = 0; g < 3; ++g) acc[mt][g] = (f32x4){0.f, 0.f, 0.f, 0.f};
      #pragma unroll 2
      for (int kf = 0; kf < 16; ++kf) {
        f16x8 B[2];
        B[0] = *(const f16x8*)(sm + cur + ((kf * 2 + 0) << 10) + lane * 16);
        B[1] = *(const f16x8*)(sm + cur + ((kf * 2 + 1) << 10) + lane * 16);
        #pragma unroll
        for (int g = 0; g < 3; ++g) {
          const f16x8 A = *(const f16x8*)(whh + (g * 512 + jt + l16) * 512 + kf * 32 + l4 * 8);
          acc[0][g] = __builtin_amdgcn_mfma_f32_16x16x32_f16(A, B[0], acc[0][g], 0, 0, 0);
          acc[1][g] = __builtin_amdgcn_mfma_f32_16x16x32_f16(A, B[1], acc[1][g], 0, 0, 0);
        }
      }
      if (q == 0) __syncthreads();  // B5: sm_x(t) visible (hidden behind q0 MFMA)
      const int jq = jt + l4 * 4;
      const f16x4 wrh = *(const f16x4*)(sm_c7 + jq);
      const f16x4 wzh = *(const f16x4*)(sm_c7 + 512 + jq);
      const f16x4 wnh = *(const f16x4*)(sm_c7 + 1024 + jq);
      const f16x4 crh = *(const f16x4*)(sm_c7 + 1536 + jq);
      const f16x4 czh = *(const f16x4*)(sm_c7 + 2048 + jq);
      const f16x4 bnh = *(const f16x4*)(sm_c7 + 2560 + jq);
      const f16x4 cnh = *(const f16x4*)(sm_c7 + 3072 + jq);
      #pragma unroll
      for (int mt = 0; mt < 2; ++mt) {
        const int m = mt * 16 + l16;
        const float x = sm_x[m];
        const int hoff = fa32(m, jq);
        const f16x4 ho = *(const f16x4*)(sm + cur + hoff);
        f16x4 hn;
        #pragma unroll
        for (int r = 0; r < 4; ++r) {
          const float gr = sigm(x * (float)wrh[r] + (float)crh[r] + acc[mt][0][r]);
          const float gz = sigm(x * (float)wzh[r] + (float)czh[r] + acc[mt][1][r]);
          const float gn = tanh_s(x * (float)wnh[r] + (float)bnh[r] + gr * (acc[mt][2][r] + (float)cnh[r]));
          hn[r] = (f16)((1.f - gz) * gn + gz * (float)ho[r]);
        }
        *(f16x4*)(sm + nxt + hoff) = hn;
      }
    }
    __syncthreads();  // B2: h[nxt] complete
    // ---- G2: y = gelu(LN(h_new @ Wo1 + bo1)) @ Wo2 + bo2 ------------------
    {
      const int mg = w >> 2, jg = w & 3;   // 2 m-groups x 4 j-groups
      f32x4 a2[4];  // [jt2] — one m-tile per wave
      #pragma unroll
      for (int jt2 = 0; jt2 < 4; ++jt2) a2[jt2] = (f32x4){0.f, 0.f, 0.f, 0.f};
      #pragma unroll 2
      for (int kf = 0; kf < 16; ++kf) {
        const f16x8 B = *(const f16x8*)(sm + nxt + ((kf * 2 + mg) << 10) + lane * 16);
        #pragma unroll
        for (int jt2 = 0; jt2 < 4; ++jt2) {
          const f16x8 A = *(const f16x8*)(wo1t + (jg * 64 + jt2 * 16 + l16) * 512 + kf * 32 + l4 * 8);
          a2[jt2] = __builtin_amdgcn_mfma_f32_16x16x32_f16(A, B, a2[jt2], 0, 0, 0);
        }
      }
      float vv[4][4];
      float s = 0.f, ss = 0.f;
      #pragma unroll
      for (int jt2 = 0; jt2 < 4; ++jt2) {
        const f16x4 bo1v = *(const f16x4*)(sm_aux + jg * 64 + jt2 * 16 + l4 * 4);
        #pragma unroll
        for (int r = 0; r < 4; ++r) {
          const float v = a2[jt2][r] + (float)bo1v[r];
          vv[jt2][r] = v; s += v; ss += v * v;
        }
      }
      s += __shfl_xor(s, 16); ss += __shfl_xor(ss, 16);
      s += __shfl_xor(s, 32); ss += __shfl_xor(ss, 32);
      if (l4 == 0) {
        const int m = mg * 16 + l16;
        sm_s[m * 4 + jg] = s;
        sm_ss[m * 4 + jg] = ss;
      }
      __syncthreads();  // B3: stats partials visible
      {
        const int m = mg * 16 + l16;
        float4 ps = *(const float4*)(sm_s + m * 4);
        float4 pq = *(const float4*)(sm_ss + m * 4);
        const float mean = (ps.x + ps.y + ps.z + ps.w) * (1.f / 256.f);
        const float q2 = (pq.x + pq.y + pq.z + pq.w) * (1.f / 256.f);
        const float rstd = rsqrtf(q2 - mean * mean + 1e-5f);
        float y = 0.f;
        #pragma unroll
        for (int jt2 = 0; jt2 < 4; ++jt2) {
          const int jb = jg * 64 + jt2 * 16 + l4 * 4;
          const f16x4 gov = *(const f16x4*)(sm_aux + 256 + jb);
          const f16x4 bev = *(const f16x4*)(sm_aux + 512 + jb);
          const f16x4 wv  = *(const f16x4*)(sm_aux + 768 + jb);
          #pragma unroll
          for (int r = 0; r < 4; ++r)
            y += gelu_e((vv[jt2][r] - mean) * rstd * (float)gov[r] + (float)bev[r]) * (float)wv[r];
        }
        y += __shfl_xor(y, 16);
        y += __shfl_xor(y, 32);
        if (l4 == 0) sm_yp[m * 4 + jg] = y;
      }
      __syncthreads();  // B4: y partials visible
      if (tid < 32) {
        float4 ps = *(const float4*)(sm_yp + tid * 4);
        const float y = bo2v + ps.x + ps.y + ps.z + ps.w;
        sm_x[tid] = y;
        out[(R0 + tid) * 20 + t] = y;
      }
      // next step's B5 (inside q0) covers sm_x visibility
    }
  }
}

// ---------------------------------------------------------------------------
extern "C" void kernel_launch(void* const* d_in, const int* in_sizes, int n_in,
                              void* d_out, int out_size, void* d_ws, size_t ws_size,
                              hipStream_t stream) {
  const float* zq   = (const float*)d_in[0];
  const float* fpr  = (const float*)d_in[1];
  const float* W1   = (const float*)d_in[2];
  const float* b1   = (const float*)d_in[3];
  const float* g1   = (const float*)d_in[4];
  const float* be1  = (const float*)d_in[5];
  const float* W2   = (const float*)d_in[6];
  const float* b2   = (const float*)d_in[7];
  const float* stok = (const float*)d_in[8];
  const float* Wih  = (const float*)d_in[9];
  const float* Whh  = (const float*)d_in[10];
  const float* bih  = (const float*)d_in[11];
  const float* bhh  = (const float*)d_in[12];
  const float* Wo1  = (const float*)d_in[13];
  const float* bo1  = (const float*)d_in[14];
  const float* go   = (const float*)d_in[15];
  const float* beo  = (const float*)d_in[16];
  const float* Wo2  = (const float*)d_in[17];
  const float* bo2  = (const float*)d_in[18];

  char* ws = (char*)d_ws;
  f16* w1t  = (f16*)(ws + 0);        // 1024*160*2  = 327680
  f16* w2t  = (f16*)(ws + 327680);   // 512*1024*2  = 1048576
  f16* whh  = (f16*)(ws + 1376256);  // 1536*512*2  = 1572864
  f16* wo1t = (f16*)(ws + 2949120);  // 256*512*2   = 262144
  f16* c7   = (f16*)(ws + 3211264);  // 7*512*2     = 7168   (total ~3.2MB)

  cvt_weights<<<6287, 256, 0, stream>>>(W1, W2, Whh, Wo1, Wih, bih, bhh,
                                        w1t, w2t, whh, wo1t, c7);

  const int N = in_sizes[0] / 128;  // 65536 rows
  gru_main<<<N / 32, 512, 0, stream>>>(zq, fpr, b1, g1, be1, b2, stok,
                                       bo1, go, beo, Wo2, bo2,
                                       w1t, w2t, whh, wo1t, c7, (float*)d_out);
}

// Round 13
// 9016.267 us; speedup vs baseline: 1.4222x; 1.0280x over previous
//
#include <hip/hip_runtime.h>
#include <math.h>

// ---------------------------------------------------------------------------
// SequencePredictorGRU — fused persistent kernel, fp16 MFMA, fp32 accum.
// R13: WAVE-SPECIALIZED PIPELINE. R12 proved occupancy/spill/conflicts are all
// non-binding — the limiter is the serial per-step phase chain (~168K cyc vs
// 35K MFMA floor). Exploit: G2(h(t)) = y(t-1) = x(t) needs only h(t), same
// input G1's MFMA reads. So waves 0-3 run G1 (h(t)->h(t+1)) while waves 4-7
// run G2 (h(t)->x(t)) CONCURRENTLY; A's blend (the only consumer of x(t))
// waits on one mid-step barrier. 2 barriers/step (was 4); G2's MFMA+LN+gelu
// leave the critical path entirely (B's LN/y reductions are in-wave shuffles,
// no LDS). 21 iterations: B trails A by one step; iter 20 = y(19) epilogue.
// Base structure = R9 (64 rows, dbuf h 2x64KB frag-order, 512thr, LB(512,2)
// = the verified 128-reg budget config; c7/aux staged in LDS).
// Frag-order h: chunk((k>>5)*4+(m>>4))*1024 + ((m&15)+((k>>3)&3)*16)*16
//  + (k&7)*2; B-frag read = base + chunk*1024 + lane*16 (conflict-free).
// MFMA 16x16x32 layouts (verified R1-R12):
//   A: row=l&15, k=(l>>4)*8+i     B: col=l&15, k=(l>>4)*8+i
//   D: col=l&15 (-> m row), row=(l>>4)*4+r (-> j, contiguous quad)
// ---------------------------------------------------------------------------

typedef _Float16 f16;
typedef _Float16 f16x4 __attribute__((ext_vector_type(4)));
typedef _Float16 f16x8 __attribute__((ext_vector_type(8)));
typedef float f32x4 __attribute__((ext_vector_type(4)));

#define TSTEPS 20

__device__ __forceinline__ float sigm(float v) { return 1.0f / (1.0f + __expf(-v)); }
__device__ __forceinline__ float tanh_s(float v) {
  float e = __expf(-2.0f * fabsf(v));
  float r = (1.0f - e) / (1.0f + e);
  return copysignf(r, v);
}
__device__ __forceinline__ float gelu_e(float v) {
  return 0.5f * v * (1.0f + erff(v * 0.70710678118654752f));
}
__device__ __forceinline__ void st4(float* d, float4 v) {
  d[0] = v.x; d[1] = v.y; d[2] = v.z; d[3] = v.w;
}

// frag-order byte address (m,k); h: k<512 (64KB/buffer); t1: k<1024 (128KB)
__device__ __forceinline__ int fa(int m, int k) {
  return (((k >> 5) * 4 + (m >> 4)) << 10) + (((m & 15) + ((k >> 3) & 3) * 16) << 4) + ((k & 7) * 2);
}

// G1 MFMA body: 16 kf, B[4] shared across 3 gates, into ACC[4][3]
#define G1_MFMA(ACC, JT)                                                        \
  {                                                                             \
    _Pragma("unroll 2")                                                         \
    for (int kf = 0; kf < 16; ++kf) {                                           \
      f16x8 Bf[4];                                                              \
      _Pragma("unroll")                                                         \
      for (int mt = 0; mt < 4; ++mt)                                            \
        Bf[mt] = *(const f16x8*)(sm + cur + ((kf * 4 + mt) << 10) + lane * 16); \
      _Pragma("unroll")                                                         \
      for (int g = 0; g < 3; ++g) {                                             \
        const f16x8 Af = *(const f16x8*)(whh + (g * 512 + (JT) + l16) * 512 + kf * 32 + l4 * 8); \
        _Pragma("unroll")                                                       \
        for (int mt = 0; mt < 4; ++mt)                                          \
          ACC[mt][g] = __builtin_amdgcn_mfma_f32_16x16x32_f16(Af, Bf[mt], ACC[mt][g], 0, 0, 0); \
      }                                                                         \
    }                                                                           \
  }

// G1 blend + write h(t+1) slice to nxt
#define G1_BLEND(ACC, JT)                                                       \
  {                                                                             \
    const int jq = (JT) + l4 * 4;                                               \
    const f16x4 wrh = *(const f16x4*)(sm_c7 + jq);                              \
    const f16x4 wzh = *(const f16x4*)(sm_c7 + 512 + jq);                        \
    const f16x4 wnh = *(const f16x4*)(sm_c7 + 1024 + jq);                       \
    const f16x4 crh = *(const f16x4*)(sm_c7 + 1536 + jq);                       \
    const f16x4 czh = *(const f16x4*)(sm_c7 + 2048 + jq);                       \
    const f16x4 bnh = *(const f16x4*)(sm_c7 + 2560 + jq);                       \
    const f16x4 cnh = *(const f16x4*)(sm_c7 + 3072 + jq);                       \
    _Pragma("unroll")                                                           \
    for (int mt = 0; mt < 4; ++mt) {                                            \
      const int m = mt * 16 + l16;                                              \
      const float x = sm_x[m];                                                  \
      const int hoff = fa(m, jq);                                               \
      const f16x4 ho = *(const f16x4*)(sm + cur + hoff);                        \
      f16x4 hn;                                                                 \
      _Pragma("unroll")                                                         \
      for (int r = 0; r < 4; ++r) {                                             \
        const float gr = sigm(x * (float)wrh[r] + (float)crh[r] + ACC[mt][0][r]); \
        const float gz = sigm(x * (float)wzh[r] + (float)czh[r] + ACC[mt][1][r]); \
        const float gn = tanh_s(x * (float)wnh[r] + (float)bnh[r] + gr * (ACC[mt][2][r] + (float)cnh[r])); \
        hn[r] = (f16)((1.f - gz) * gn + gz * (float)ho[r]);                     \
      }                                                                         \
      *(f16x4*)(sm + nxt + hoff) = hn;                                          \
    }                                                                           \
  }

// ---------------------------------------------------------------------------
// Prologue: fp16 weights (K-contiguous) + packed f16 gate coefficients.
// c7 layout [7][512]: 0 Wih_r, 1 Wih_z, 2 Wih_n, 3 bih_r+bhh_r, 4 bih_z+bhh_z,
//                     5 bih_n, 6 bhh_n
// ---------------------------------------------------------------------------
__global__ void cvt_weights(const float* __restrict__ W1, const float* __restrict__ W2,
                            const float* __restrict__ Whh, const float* __restrict__ Wo1,
                            const float* __restrict__ Wih, const float* __restrict__ bih,
                            const float* __restrict__ bhh,
                            f16* __restrict__ w1t, f16* __restrict__ w2t,
                            f16* __restrict__ whh, f16* __restrict__ wo1t,
                            f16* __restrict__ c7) {
  int i = blockIdx.x * 256 + threadIdx.x;
  if (i < 163840) { int n = i / 160; int k = i - n * 160; w1t[i] = (f16)W1[k * 1024 + n]; return; }
  i -= 163840;
  if (i < 524288) { int n = i >> 10; int k = i & 1023; w2t[i] = (f16)W2[k * 512 + n]; return; }
  i -= 524288;
  if (i < 786432) { whh[i] = (f16)Whh[i]; return; }
  i -= 786432;
  if (i < 131072) { int o = i >> 9; int k = i & 511; wo1t[i] = (f16)Wo1[k * 256 + o]; return; }
  i -= 131072;
  if (i < 3584) {
    const int which = i >> 9, j = i & 511;
    float v;
    if (which == 0) v = Wih[j];
    else if (which == 1) v = Wih[512 + j];
    else if (which == 2) v = Wih[1024 + j];
    else if (which == 3) v = bih[j] + bhh[j];
    else if (which == 4) v = bih[512 + j] + bhh[512 + j];
    else if (which == 5) v = bih[1024 + j];
    else v = bhh[1024 + j];
    c7[i] = (f16)v;
  }
}

// ---------------------------------------------------------------------------
// Main fused kernel: 512 threads = 8 waves, 64 rows/block, 1 block/CU.
// Waves 0-3: G1 (recurrence). Waves 4-7: G2 (output MLP), one step behind.
// ---------------------------------------------------------------------------
__global__ __launch_bounds__(512, 2)
void gru_main(
    const float* __restrict__ zq, const float* __restrict__ fpr,
    const float* __restrict__ b1, const float* __restrict__ g1, const float* __restrict__ be1,
    const float* __restrict__ b2, const float* __restrict__ stok,
    const float* __restrict__ bo1, const float* __restrict__ go, const float* __restrict__ beo,
    const float* __restrict__ Wo2, const float* __restrict__ bo2,
    const f16* __restrict__ w1t, const f16* __restrict__ w2t,
    const f16* __restrict__ whh, const f16* __restrict__ wo1t,
    const f16* __restrict__ c7,
    float* __restrict__ out) {
  __shared__ __align__(16) unsigned char sm[131072];  // h dbuf 2x64KB / t1 128KB
  __shared__ float sm_s[256], sm_ss[256];
  __shared__ float sm_x[64];
  __shared__ __align__(8) f16 sm_c7[3584];
  __shared__ __align__(8) f16 sm_aux[1024];  // bo1|go|beo|Wo2 (f16), 256 each

  const int tid = threadIdx.x;
  const int w = tid >> 6;        // 0..7
  const int lane = tid & 63;
  const int l16 = lane & 15;
  const int l4 = lane >> 4;
  const int R0 = blockIdx.x * 64;

  const float bo2v = bo2[0];
  if (tid < 64) sm_x[tid] = stok[0];
  for (int i = tid; i < 1792; i += 512)
    ((unsigned*)sm_c7)[i] = ((const unsigned*)c7)[i];
  for (int i = tid; i < 1024; i += 512) {
    const float v = (i < 256) ? bo1[i] : (i < 512) ? go[i - 256] : (i < 768) ? beo[i - 512] : Wo2[i - 768];
    sm_aux[i] = (f16)v;
  }

  // ================= G0a: t1 = cat(zq,fpr) @ W1 + b1 (frag order) =========
  #pragma unroll 1
  for (int p = 0; p < 4; ++p) {
    #pragma unroll 1
    for (int jh = 0; jh < 2; ++jh) {
      const int jq0 = w * 128 + p * 32 + jh * 16;
      f32x4 acc[4];
      #pragma unroll
      for (int mt = 0; mt < 4; ++mt) acc[mt] = (f32x4){0.f, 0.f, 0.f, 0.f};
      #pragma unroll
      for (int kf = 0; kf < 5; ++kf) {
        const int k0 = kf * 32 + l4 * 8;
        f16x8 B[4];
        #pragma unroll
        for (int mt = 0; mt < 4; ++mt) {
          const int gm = R0 + mt * 16 + l16;
          const float* src = (kf < 4) ? (zq + gm * 128 + k0) : (fpr + gm * 32 + (k0 - 128));
          float4 v0 = *(const float4*)src;
          float4 v1 = *(const float4*)(src + 4);
          f16x8 b;
          b[0] = (f16)v0.x; b[1] = (f16)v0.y; b[2] = (f16)v0.z; b[3] = (f16)v0.w;
          b[4] = (f16)v1.x; b[5] = (f16)v1.y; b[6] = (f16)v1.z; b[7] = (f16)v1.w;
          B[mt] = b;
        }
        const f16x8 A = *(const f16x8*)(w1t + (jq0 + l16) * 160 + k0);
        #pragma unroll
        for (int mt = 0; mt < 4; ++mt)
          acc[mt] = __builtin_amdgcn_mfma_f32_16x16x32_f16(A, B[mt], acc[mt], 0, 0, 0);
      }
      const int jq = jq0 + l4 * 4;
      float bb[4]; st4(bb, *(const float4*)(b1 + jq));
      #pragma unroll
      for (int mt = 0; mt < 4; ++mt) {
        f16x4 v;
        #pragma unroll
        for (int r = 0; r < 4; ++r) v[r] = (f16)(acc[mt][r] + bb[r]);
        *(f16x4*)(sm + fa(mt * 16 + l16, jq)) = v;
      }
    }
  }
  __syncthreads();
  // ================= LN(1024) + GELU in place (frag chunks) ================
  {
    const int mt = w & 3, half = w >> 2;
    const int row = mt * 16 + l16;
    float s = 0.f, ss = 0.f;
    #pragma unroll 4
    for (int it = 0; it < 16; ++it) {
      const int kb = half * 16 + it;
      f16x8 v = *(const f16x8*)(sm + (kb * 4 + mt) * 1024 + lane * 16);
      #pragma unroll
      for (int i = 0; i < 8; ++i) { float f = (float)v[i]; s += f; ss += f * f; }
    }
    s += __shfl_xor(s, 16); ss += __shfl_xor(ss, 16);
    s += __shfl_xor(s, 32); ss += __shfl_xor(ss, 32);
    if (l4 == 0) { sm_s[row * 2 + half] = s; sm_ss[row * 2 + half] = ss; }
    __syncthreads();
    const float mean = (sm_s[row * 2] + sm_s[row * 2 + 1]) * (1.f / 1024.f);
    const float q2 = (sm_ss[row * 2] + sm_ss[row * 2 + 1]) * (1.f / 1024.f);
    const float rstd = rsqrtf(q2 - mean * mean + 1e-5f);
    #pragma unroll 2
    for (int it = 0; it < 16; ++it) {
      const int kb = half * 16 + it;
      const int off = (kb * 4 + mt) * 1024 + lane * 16;
      const int c = kb * 32 + l4 * 8;
      f16x8 v = *(const f16x8*)(sm + off);
      float4 ga = *(const float4*)(g1 + c);
      float4 gb = *(const float4*)(g1 + c + 4);
      float4 ba = *(const float4*)(be1 + c);
      float4 bb = *(const float4*)(be1 + c + 4);
      float gs[8] = {ga.x, ga.y, ga.z, ga.w, gb.x, gb.y, gb.z, gb.w};
      float bs[8] = {ba.x, ba.y, ba.z, ba.w, bb.x, bb.y, bb.z, bb.w};
      f16x8 o;
      #pragma unroll
      for (int j = 0; j < 8; ++j)
        o[j] = (f16)gelu_e(((float)v[j] - mean) * rstd * gs[j] + bs[j]);
      *(f16x8*)(sm + off) = o;
    }
  }
  __syncthreads();
  // ================= G0b: h0 = tanh(t1g @ W2 + b2) -> regs =================
  f16x4 hold[4][4];  // [pp][mt] — statically indexed
  #pragma unroll
  for (int pp = 0; pp < 4; ++pp) {
    const int jq0 = w * 64 + pp * 16;
    f32x4 acc[4];
    #pragma unroll
    for (int mt = 0; mt < 4; ++mt) acc[mt] = (f32x4){0.f, 0.f, 0.f, 0.f};
    #pragma unroll 2
    for (int kf = 0; kf < 32; ++kf) {
      f16x8 B[4];
      #pragma unroll
      for (int mt = 0; mt < 4; ++mt)
        B[mt] = *(const f16x8*)(sm + ((kf * 4 + mt) << 10) + lane * 16);
      const f16x8 A = *(const f16x8*)(w2t + (jq0 + l16) * 1024 + kf * 32 + l4 * 8);
      #pragma unroll
      for (int mt = 0; mt < 4; ++mt)
        acc[mt] = __builtin_amdgcn_mfma_f32_16x16x32_f16(A, B[mt], acc[mt], 0, 0, 0);
    }
    const int jq = jq0 + l4 * 4;
    float bb[4]; st4(bb, *(const float4*)(b2 + jq));
    #pragma unroll
    for (int mt = 0; mt < 4; ++mt) {
      f16x4 v;
      #pragma unroll
      for (int r = 0; r < 4; ++r) v[r] = (f16)tanh_s(acc[mt][r] + bb[r]);
      hold[pp][mt] = v;
    }
  }
  __syncthreads();  // all t1 reads done; region reusable as h dbuf
  #pragma unroll
  for (int pp = 0; pp < 4; ++pp) {
    const int jq = w * 64 + pp * 16 + l4 * 4;
    #pragma unroll
    for (int mt = 0; mt < 4; ++mt)
      *(f16x4*)(sm + fa(mt * 16 + l16, jq)) = hold[pp][mt];  // buffer 0 = h(0)
  }
  __syncthreads();

  // ================== GRU pipeline: 21 iterations ==========================
  // iter t: waves 0-3 (A): h(t) -> h(t+1) [t<20]; waves 4-7 (B): G2(h(t)) =
  // y(t-1) = x(t) [t>=1]. A's blend (needs x(t)) runs after barrier beta.
  #pragma unroll 1
  for (int t = 0; t <= TSTEPS; ++t) {
    const int cur = (t & 1) << 16;
    const int nxt = cur ^ 65536;
    const int jt0 = w * 128;  // A-wave j-slice base (valid for w<4)
    f32x4 acc0[4][3];
    if (w < 4) {
      if (t < TSTEPS) {
        // ---- A: pass 0 MFMA (blend deferred past beta) --------------------
        #pragma unroll
        for (int mt = 0; mt < 4; ++mt)
          #pragma unroll
          for (int g = 0; g < 3; ++g) acc0[mt][g] = (f32x4){0.f, 0.f, 0.f, 0.f};
        G1_MFMA(acc0, jt0)
      }
    } else {
      if (t >= 1) {
        // ---- B: G2 on h(t) -> y(t-1) = x(t), all in-wave ------------------
        const int b = w - 4;  // m-tile
        f32x4 a2[16];
        #pragma unroll
        for (int jt = 0; jt < 16; ++jt) a2[jt] = (f32x4){0.f, 0.f, 0.f, 0.f};
        #pragma unroll 1
        for (int kf = 0; kf < 16; ++kf) {
          const f16x8 B = *(const f16x8*)(sm + cur + ((kf * 4 + b) << 10) + lane * 16);
          #pragma unroll
          for (int jt = 0; jt < 16; ++jt) {
            const f16x8 A = *(const f16x8*)(wo1t + (jt * 16 + l16) * 512 + kf * 32 + l4 * 8);
            a2[jt] = __builtin_amdgcn_mfma_f32_16x16x32_f16(A, B, a2[jt], 0, 0, 0);
          }
        }
        // v = a2 + bo1 (in place); stats over the row's 256 values
        float s = 0.f, ss = 0.f;
        #pragma unroll
        for (int jt = 0; jt < 16; ++jt) {
          const f16x4 bb = *(const f16x4*)(sm_aux + jt * 16 + l4 * 4);
          #pragma unroll
          for (int r = 0; r < 4; ++r) {
            const float v = a2[jt][r] + (float)bb[r];
            a2[jt][r] = v; s += v; ss += v * v;
          }
        }
        s += __shfl_xor(s, 16); ss += __shfl_xor(ss, 16);
        s += __shfl_xor(s, 32); ss += __shfl_xor(ss, 32);
        const float mean = s * (1.f / 256.f);
        const float rstd = rsqrtf(ss * (1.f / 256.f) - mean * mean + 1e-5f);
        float y = 0.f;
        #pragma unroll
        for (int jt = 0; jt < 16; ++jt) {
          const int jb = jt * 16 + l4 * 4;
          const f16x4 gov = *(const f16x4*)(sm_aux + 256 + jb);
          const f16x4 bev = *(const f16x4*)(sm_aux + 512 + jb);
          const f16x4 wv  = *(const f16x4*)(sm_aux + 768 + jb);
          #pragma unroll
          for (int r = 0; r < 4; ++r)
            y += gelu_e((a2[jt][r] - mean) * rstd * (float)gov[r] + (float)bev[r]) * (float)wv[r];
        }
        y += __shfl_xor(y, 16);
        y += __shfl_xor(y, 32);
        if (l4 == 0) {
          const int m = b * 16 + l16;
          const float yy = y + bo2v;
          sm_x[m] = yy;                       // x(t) for A's blend
          out[(R0 + m) * 20 + (t - 1)] = yy;  // y(t-1)
        }
      }
    }
    __syncthreads();  // beta: x(t) visible; h(t) untouched
    if (w < 4 && t < TSTEPS) {
      G1_BLEND(acc0, jt0)
      #pragma unroll 1
      for (int q = 1; q < 8; ++q) {
        const int jt = jt0 + q * 16;
        f32x4 acc[4][3];
        #pragma unroll
        for (int mt = 0; mt < 4; ++mt)
          #pragma unroll
          for (int g = 0; g < 3; ++g) acc[mt][g] = (f32x4){0.f, 0.f, 0.f, 0.f};
        G1_MFMA(acc, jt)
        G1_BLEND(acc, jt)
      }
    }
    __syncthreads();  // gamma: h(t+1) complete
  }
}

// ---------------------------------------------------------------------------
extern "C" void kernel_launch(void* const* d_in, const int* in_sizes, int n_in,
                              void* d_out, int out_size, void* d_ws, size_t ws_size,
                              hipStream_t stream) {
  const float* zq   = (const float*)d_in[0];
  const float* fpr  = (const float*)d_in[1];
  const float* W1   = (const float*)d_in[2];
  const float* b1   = (const float*)d_in[3];
  const float* g1   = (const float*)d_in[4];
  const float* be1  = (const float*)d_in[5];
  const float* W2   = (const float*)d_in[6];
  const float* b2   = (const float*)d_in[7];
  const float* stok = (const float*)d_in[8];
  const float* Wih  = (const float*)d_in[9];
  const float* Whh  = (const float*)d_in[10];
  const float* bih  = (const float*)d_in[11];
  const float* bhh  = (const float*)d_in[12];
  const float* Wo1  = (const float*)d_in[13];
  const float* bo1  = (const float*)d_in[14];
  const float* go   = (const float*)d_in[15];
  const float* beo  = (const float*)d_in[16];
  const float* Wo2  = (const float*)d_in[17];
  const float* bo2  = (const float*)d_in[18];

  char* ws = (char*)d_ws;
  f16* w1t  = (f16*)(ws + 0);        // 1024*160*2  = 327680
  f16* w2t  = (f16*)(ws + 327680);   // 512*1024*2  = 1048576
  f16* whh  = (f16*)(ws + 1376256);  // 1536*512*2  = 1572864
  f16* wo1t = (f16*)(ws + 2949120);  // 256*512*2   = 262144
  f16* c7   = (f16*)(ws + 3211264);  // 7*512*2     = 7168   (total ~3.2MB)

  cvt_weights<<<6287, 256, 0, stream>>>(W1, W2, Whh, Wo1, Wih, bih, bhh,
                                        w1t, w2t, whh, wo1t, c7);

  const int N = in_sizes[0] / 128;  // 65536 rows
  gru_main<<<N / 64, 512, 0, stream>>>(zq, fpr, b1, g1, be1, b2, stok,
                                       bo1, go, beo, Wo2, bo2,
                                       w1t, w2t, whh, wo1t, c7, (float*)d_out);
}